// Round 6
// baseline (297.590 us; speedup 1.0000x reference)
//
#include <hip/hip_runtime.h>
#include <math.h>

// ---------------------------------------------------------------------------
// B=64 graphs, NN=133 nodes. R-quadgemm: one block per graph (64 x 1024thr),
// round-4 dataflow (absmax 0.0) with the GEMM inner loop rebuilt per the
// round-4 counters (VALUBusy 52% active, LDS-pipe saturated by b64 A-
// broadcasts + splat movs + unpipelined W loads):
//  - A-broadcast reads: ds_read_b128 (4 k's per instr, half the LDS instrs).
//  - v_pk_fma_f32 with op_sel broadcast (inline asm): A halves broadcast
//    directly from the b128 pair registers -> zero splat movs.
//  - LDA/N/K as template params: A-addresses fold to ds-offset immediates,
//    W walks by pointer bump with imm offsets; #pragma unroll 2 lets the
//    compiler software-pipeline W loads.
//  - strides 130->132, 78->80 for 16B alignment; staging copies float4.
// Accumulation order unchanged (ascending k) => bit-identical to round 4.
// LDS: SCR 80.9KB + pairs 68.1KB + misc ~2.2KB = 151.5KB.
// ---------------------------------------------------------------------------

#define NN 133
#define NPAIR 64
#define NW 16

typedef float v2f __attribute__((ext_vector_type(2)));
typedef float v4f __attribute__((ext_vector_type(4)));

struct Params {
    const float *x, *adj, *emb_w, *emb_b, *gc1_w, *gc1_b, *gc2_w, *gc2_b,
                *gc3_w, *gc3_b, *gc4_w, *gc4_b, *fc1_w, *fc1_b, *fin_w, *fin_b;
    float *bA, *bB, *bC;
    float *out;
};

// pk-fma with src0 broadcast from one 32-bit half (no splat movs).
// blo: both result halves use src0.lo ; bhi: both use src0.hi
__device__ __forceinline__ void pk_fma_blo(v2f& acc, v2f a, v2f w)
{
    asm("v_pk_fma_f32 %0, %1, %2, %0 op_sel:[0,0,0] op_sel_hi:[0,1,1]"
        : "+v"(acc) : "v"(a), "v"(w));
}
__device__ __forceinline__ void pk_fma_bhi(v2f& acc, v2f a, v2f w)
{
    asm("v_pk_fma_f32 %0, %1, %2, %0 op_sel:[1,0,0] op_sel_hi:[1,1,1]"
        : "+v"(acc) : "v"(a), "v"(w));
}

// -------- ballot prep into LDS: front=a>1e-5, back=0<a<=1e-5 ----------------
__device__ __forceinline__ void prep_row_l(
    const float* __restrict__ ar, float2* __restrict__ pb,
    int2* __restrict__ cS, int r, int lane)
{
    const unsigned long long lt = (1ull << lane) - 1ull;
    int base0 = 0, base1 = 0;
#pragma unroll
    for (int s = 0; s < 3; ++s) {
        const int j = lane + 64 * s;
        const float a = (j < NN) ? ar[j] : 0.f;
        const bool f = a > 1e-5f;
        const bool g = (a > 0.f) && !f;
        const unsigned long long mf = __ballot(f);
        const unsigned long long mg = __ballot(g);
        if (f) pb[base0 + __popcll(mf & lt)] =
                   make_float2(a, __int_as_float(j));
        if (g) pb[(NPAIR - 1) - (base1 + __popcll(mg & lt))] =
                   make_float2(a, __int_as_float(j));
        base0 += __popcll(mf);
        base1 += __popcll(mg);
    }
    if (lane == 0) cS[r] = make_int2(base0, base1);
}

// -------- GEMM accumulate: A in LDS (b128 broadcast), op_sel pk-fma ---------
// Lane cols: chunk g covers c = g*128 + 2*lane (v2f). WVEC=false (odd N):
// W loaded as two clamped scalars. acc order: k ascending (ref-identical).
template<int LDA, int N, int K, int CHUNKS, bool WVEC>
__device__ __forceinline__ void gemm_acc(
    const float* __restrict__ A,      // LDS, row 0, stride LDA (mult of 4)
    const float* __restrict__ W,      // global [K][N] (pre-offset by caller)
    v2f (&acc)[9][CHUNKS], int rbase, int lane)
{
    const float* Ab = A + rbase * LDA;
    int co[CHUNKS], co1[CHUNKS];
#pragma unroll
    for (int g = 0; g < CHUNKS; ++g) {
        int c = g * 128 + 2 * lane;
        co[g]  = WVEC ? min(c, (N - 2) & ~1) : min(c, N - 1);
        co1[g] = WVEC ? 0 : min(c + 1, N - 1);
    }
    const float* wp[CHUNKS];
    const float* wp1[CHUNKS];
#pragma unroll
    for (int g = 0; g < CHUNKS; ++g) {
        wp[g]  = W + co[g];
        wp1[g] = WVEC ? W : (W + co1[g]);
    }
    constexpr int KQ = K & ~3;
#pragma unroll 2
    for (int k = 0; k < KQ; k += 4) {
        v2f w[4][CHUNKS];
#pragma unroll
        for (int q = 0; q < 4; ++q)
#pragma unroll
            for (int g = 0; g < CHUNKS; ++g) {
                if (WVEC) {
                    w[q][g] = *reinterpret_cast<const v2f*>(wp[g] + q * N);
                } else {
                    w[q][g].x = wp[g][q * N];
                    w[q][g].y = wp1[g][q * N];
                }
            }
#pragma unroll
        for (int g = 0; g < CHUNKS; ++g) {
            wp[g] += 4 * N;
            if (!WVEC) wp1[g] += 4 * N;
        }
#pragma unroll
        for (int i = 0; i < 9; ++i) {
            v4f a4 = *reinterpret_cast<const v4f*>(Ab + i * LDA + k);
            v2f a01 = __builtin_shufflevector(a4, a4, 0, 1);
            v2f a23 = __builtin_shufflevector(a4, a4, 2, 3);
#pragma unroll
            for (int g = 0; g < CHUNKS; ++g) {
                pk_fma_blo(acc[i][g], a01, w[0][g]);
                pk_fma_bhi(acc[i][g], a01, w[1][g]);
                pk_fma_blo(acc[i][g], a23, w[2][g]);
                pk_fma_bhi(acc[i][g], a23, w[3][g]);
            }
        }
    }
    if constexpr (K - KQ > 0) {                 // remainder 1..3 rows of W
        constexpr int R = K - KQ;
        v2f w[3][CHUNKS];
#pragma unroll
        for (int j = 0; j < R; ++j)
#pragma unroll
            for (int g = 0; g < CHUNKS; ++g) {
                if (WVEC) {
                    w[j][g] = *reinterpret_cast<const v2f*>(wp[g] + j * N);
                } else {
                    w[j][g].x = wp[g][j * N];
                    w[j][g].y = wp1[g][j * N];
                }
            }
#pragma unroll
        for (int i = 0; i < 9; ++i) {
            v4f a4 = *reinterpret_cast<const v4f*>(Ab + i * LDA + KQ);
            v2f a01 = __builtin_shufflevector(a4, a4, 0, 1);
            v2f a23 = __builtin_shufflevector(a4, a4, 2, 3);
#pragma unroll
            for (int g = 0; g < CHUNKS; ++g) {
                if (R >= 1) pk_fma_blo(acc[i][g], a01, w[0][g]);
                if (R >= 2) pk_fma_bhi(acc[i][g], a01, w[1][g]);
                if (R >= 3) pk_fma_blo(acc[i][g], a23, w[2][g]);
            }
        }
    }
}

// -------- spmm (float4 cols, global source, N=256) --------------------------
__device__ __forceinline__ void spmm_row4(
    const float* __restrict__ tb,            // global, stride 256
    const float* __restrict__ bias,
    const float2* __restrict__ pb, int2 cc,
    float* __restrict__ yrow, int lane)
{
    const int c4 = 4 * lane;
    const float4* pq = reinterpret_cast<const float4*>(pb);
    v4f acc[4];
#pragma unroll
    for (int h = 0; h < 4; ++h) { acc[h].x = 0.f; acc[h].y = 0.f; acc[h].z = 0.f; acc[h].w = 0.f; }
    int q = 0;
    for (; q + 4 <= cc.x; q += 4) {
        float4 p0 = pq[q >> 1], p1 = pq[(q >> 1) + 1];
        float w[4]; int j[4];
        w[0] = p0.x; j[0] = __float_as_int(p0.y);
        w[1] = p0.z; j[1] = __float_as_int(p0.w);
        w[2] = p1.x; j[2] = __float_as_int(p1.y);
        w[3] = p1.z; j[3] = __float_as_int(p1.w);
#pragma unroll
        for (int h = 0; h < 4; ++h) {
            v4f r4 = *reinterpret_cast<const v4f*>(tb + (size_t)j[h] * 256 + c4);
            v4f wv; wv.x = w[h]; wv.y = w[h]; wv.z = w[h]; wv.w = w[h];
            acc[h] = __builtin_elementwise_fma(wv, r4, acc[h]);
        }
    }
    for (; q < cc.x; ++q) {
        float2 f = pb[q];
        v4f r4 = *reinterpret_cast<const v4f*>(tb + (size_t)__float_as_int(f.y) * 256 + c4);
        v4f wv; wv.x = f.x; wv.y = f.x; wv.z = f.x; wv.w = f.x;
        acc[0] = __builtin_elementwise_fma(wv, r4, acc[0]);
    }
    for (int v = 0; v < cc.y; ++v) {
        float2 f = pb[(NPAIR - 1) - v];
        v4f r4 = *reinterpret_cast<const v4f*>(tb + (size_t)__float_as_int(f.y) * 256 + c4);
        v4f wv; wv.x = f.x; wv.y = f.x; wv.z = f.x; wv.w = f.x;
        acc[0] = __builtin_elementwise_fma(wv, r4, acc[0]);
    }
    v4f s = (acc[0] + acc[1]) + (acc[2] + acc[3]);
    v4f bv = *reinterpret_cast<const v4f*>(bias + c4);
    s = s + bv;
    s.x = fmaxf(s.x, 0.f); s.y = fmaxf(s.y, 0.f);
    s.z = fmaxf(s.z, 0.f); s.w = fmaxf(s.w, 0.f);
    *reinterpret_cast<v4f*>(yrow + c4) = s;
}

// -------- pool (float4 cols, global source, N=256) --------------------------
__device__ __forceinline__ void pool_row4(
    const float* __restrict__ yb,
    const float2* __restrict__ pb, int cx,
    float* __restrict__ prow, int lane)
{
    const int c4 = 4 * lane;
    const float4* pq = reinterpret_cast<const float4*>(pb);
    v4f m[4];
#pragma unroll
    for (int h = 0; h < 4; ++h) { m[h].x = 0.f; m[h].y = 0.f; m[h].z = 0.f; m[h].w = 0.f; }
    int q = 0;
    for (; q + 4 <= cx; q += 4) {
        float4 p0 = pq[q >> 1], p1 = pq[(q >> 1) + 1];
        int j[4];
        j[0] = __float_as_int(p0.y); j[1] = __float_as_int(p0.w);
        j[2] = __float_as_int(p1.y); j[3] = __float_as_int(p1.w);
#pragma unroll
        for (int h = 0; h < 4; ++h) {
            v4f r4 = *reinterpret_cast<const v4f*>(yb + (size_t)j[h] * 256 + c4);
            m[h].x = fmaxf(m[h].x, r4.x); m[h].y = fmaxf(m[h].y, r4.y);
            m[h].z = fmaxf(m[h].z, r4.z); m[h].w = fmaxf(m[h].w, r4.w);
        }
    }
    for (; q < cx; ++q) {
        v4f r4 = *reinterpret_cast<const v4f*>(yb + (size_t)__float_as_int(pb[q].y) * 256 + c4);
        m[0].x = fmaxf(m[0].x, r4.x); m[0].y = fmaxf(m[0].y, r4.y);
        m[0].z = fmaxf(m[0].z, r4.z); m[0].w = fmaxf(m[0].w, r4.w);
    }
    v4f s;
    s.x = fmaxf(fmaxf(m[0].x, m[1].x), fmaxf(m[2].x, m[3].x));
    s.y = fmaxf(fmaxf(m[0].y, m[1].y), fmaxf(m[2].y, m[3].y));
    s.z = fmaxf(fmaxf(m[0].z, m[1].z), fmaxf(m[2].z, m[3].z));
    s.w = fmaxf(fmaxf(m[0].w, m[1].w), fmaxf(m[2].w, m[3].w));
    *reinterpret_cast<v4f*>(prow + c4) = s;
}

// -------- spmm (float2 cols, LDS source) ------------------------------------
__device__ __forceinline__ void spmm_row2(
    const float* __restrict__ tb, int ldt, int scmax,   // LDS
    const float* __restrict__ bias, int N,
    const float2* __restrict__ pb, int2 cc,
    float* __restrict__ yrow, int lane)
{
    const int c0 = 2 * lane;
    const int sc = min(c0, scmax);
    const float4* pq = reinterpret_cast<const float4*>(pb);
    v2f acc[4];
#pragma unroll
    for (int h = 0; h < 4; ++h) { acc[h].x = 0.f; acc[h].y = 0.f; }
    int q = 0;
    for (; q + 4 <= cc.x; q += 4) {
        float4 p0 = pq[q >> 1], p1 = pq[(q >> 1) + 1];
        float w[4]; int j[4];
        w[0] = p0.x; j[0] = __float_as_int(p0.y);
        w[1] = p0.z; j[1] = __float_as_int(p0.w);
        w[2] = p1.x; j[2] = __float_as_int(p1.y);
        w[3] = p1.z; j[3] = __float_as_int(p1.w);
#pragma unroll
        for (int h = 0; h < 4; ++h) {
            v2f r2 = *reinterpret_cast<const v2f*>(tb + (size_t)j[h] * ldt + sc);
            v2f wv; wv.x = w[h]; wv.y = w[h];
            acc[h] = __builtin_elementwise_fma(wv, r2, acc[h]);
        }
    }
    for (; q < cc.x; ++q) {
        float2 f = pb[q];
        v2f r2 = *reinterpret_cast<const v2f*>(tb + (size_t)__float_as_int(f.y) * ldt + sc);
        v2f wv; wv.x = f.x; wv.y = f.x;
        acc[0] = __builtin_elementwise_fma(wv, r2, acc[0]);
    }
    for (int v = 0; v < cc.y; ++v) {
        float2 f = pb[(NPAIR - 1) - v];
        v2f r2 = *reinterpret_cast<const v2f*>(tb + (size_t)__float_as_int(f.y) * ldt + sc);
        v2f wv; wv.x = f.x; wv.y = f.x;
        acc[0] = __builtin_elementwise_fma(wv, r2, acc[0]);
    }
    v2f s = (acc[0] + acc[1]) + (acc[2] + acc[3]);
    float b0 = bias[min(c0, N - 1)];
    float b1 = (c0 + 1 < N) ? bias[c0 + 1] : 0.f;
    s.x = fmaxf(s.x + b0, 0.f);
    s.y = fmaxf(s.y + b1, 0.f);
    if (c0 < N) {
        v2f o; o.x = s.x; o.y = (c0 + 1 < N) ? s.y : 0.f;
        *reinterpret_cast<v2f*>(yrow + c0) = o;
    }
}

// -------- pool (float2 cols, LDS source) ------------------------------------
__device__ __forceinline__ void pool_row2(
    const float* __restrict__ yb, int ldt, int scmax, int N,
    const float2* __restrict__ pb, int cx,
    float* __restrict__ prow, int lane)
{
    const int c0 = 2 * lane;
    const int sc = min(c0, scmax);
    const float4* pq = reinterpret_cast<const float4*>(pb);
    v2f m[4];
#pragma unroll
    for (int h = 0; h < 4; ++h) { m[h].x = 0.f; m[h].y = 0.f; }
    int q = 0;
    for (; q + 4 <= cx; q += 4) {
        float4 p0 = pq[q >> 1], p1 = pq[(q >> 1) + 1];
        int j[4];
        j[0] = __float_as_int(p0.y); j[1] = __float_as_int(p0.w);
        j[2] = __float_as_int(p1.y); j[3] = __float_as_int(p1.w);
#pragma unroll
        for (int h = 0; h < 4; ++h) {
            v2f r2 = *reinterpret_cast<const v2f*>(yb + (size_t)j[h] * ldt + sc);
            m[h].x = fmaxf(m[h].x, r2.x); m[h].y = fmaxf(m[h].y, r2.y);
        }
    }
    for (; q < cx; ++q) {
        v2f r2 = *reinterpret_cast<const v2f*>(yb + (size_t)__float_as_int(pb[q].y) * ldt + sc);
        m[0].x = fmaxf(m[0].x, r2.x); m[0].y = fmaxf(m[0].y, r2.y);
    }
    v2f s;
    s.x = fmaxf(fmaxf(m[0].x, m[1].x), fmaxf(m[2].x, m[3].x));
    s.y = fmaxf(fmaxf(m[0].y, m[1].y), fmaxf(m[2].y, m[3].y));
    if (c0 < N) {
        v2f o; o.x = s.x; o.y = (c0 + 1 < N) ? s.y : 0.f;
        *reinterpret_cast<v2f*>(prow + c0) = o;
    }
}

// -------- t4: t4S[r] = dot(pool3(y3)[r,0:75], gc4_w) ------------------------
__device__ __forceinline__ void t4_row_l(
    const float* __restrict__ yb,            // y3 global, stride 76
    const float2* __restrict__ pb, int cx,
    const float* __restrict__ gc4_w,
    float* __restrict__ t4S, int r, int lane)
{
    const float4* pq = reinterpret_cast<const float4*>(pb);
    const float gw0 = gc4_w[lane];
    const float gw1 = (lane < 11) ? gc4_w[64 + lane] : 0.f;
    const int c2 = 64 + min(lane, 10);

    float m0a = 0.f, m1a = 0.f, m0b = 0.f, m1b = 0.f;
    float m0c = 0.f, m1c = 0.f, m0d = 0.f, m1d = 0.f;
    int q = 0;
    for (; q + 4 <= cx; q += 4) {
        float4 pA = pq[q >> 1], pB = pq[(q >> 1) + 1];
        const float* r0 = yb + (size_t)__float_as_int(pA.y) * 76;
        const float* r1 = yb + (size_t)__float_as_int(pA.w) * 76;
        const float* r2 = yb + (size_t)__float_as_int(pB.y) * 76;
        const float* r3 = yb + (size_t)__float_as_int(pB.w) * 76;
        m0a = fmaxf(m0a, r0[lane]); m1a = fmaxf(m1a, r0[c2]);
        m0b = fmaxf(m0b, r1[lane]); m1b = fmaxf(m1b, r1[c2]);
        m0c = fmaxf(m0c, r2[lane]); m1c = fmaxf(m1c, r2[c2]);
        m0d = fmaxf(m0d, r3[lane]); m1d = fmaxf(m1d, r3[c2]);
    }
    for (; q < cx; ++q) {
        const float* r0 = yb + (size_t)__float_as_int(pb[q].y) * 76;
        m0a = fmaxf(m0a, r0[lane]); m1a = fmaxf(m1a, r0[c2]);
    }
    float m0 = fmaxf(fmaxf(m0a, m0b), fmaxf(m0c, m0d));
    float m1 = fmaxf(fmaxf(m1a, m1b), fmaxf(m1c, m1d));
    float v = m0 * gw0 + m1 * gw1;
#pragma unroll
    for (int off = 32; off; off >>= 1) v += __shfl_xor(v, off, 64);
    if (lane == 0) t4S[r] = v;
}

// --------------------------- one block = one graph --------------------------
__global__ __launch_bounds__(1024, 1)
void graph_k(Params P)
{
    __shared__ __align__(16) float SCR[20216];           // 80.9 KB scratch
    __shared__ __align__(16) float2 pairsS[NN][NPAIR];   // 68.1 KB
    __shared__ int2  cS[NN];
    __shared__ float t4S[NN];
    __shared__ float y4S[NN];
    __shared__ float rS[3];

    const int b    = blockIdx.x;
    const int tid  = threadIdx.x;
    const int wave = tid >> 6, lane = tid & 63;
    const int rbase = (wave * NN) >> 4;
    const int rcnt  = (((wave + 1) * NN) >> 4) - rbase;   // 8 or 9

    float* bAg = P.bA + (size_t)b * NN * 256;
    float* bBg = P.bB + (size_t)b * NN * 256;
    float* bCg = P.bC + (size_t)b * NN * 256;

    // S0: x -> SCR (stride 76, col75 zero-pad) + ballot prep -> LDS
    for (int i = tid; i < NN * 76; i += 1024) {
        int r = i / 76, c = i - r * 76;
        SCR[i] = (c < 75) ? P.x[((size_t)b * NN + r) * 75 + c] : 0.f;
    }
    for (int r = wave; r < NN; r += NW)
        prep_row_l(P.adj + ((size_t)b * NN + r) * NN, pairsS[r], cS, r, lane);
    __syncthreads();

    // S0b: emb = relu(x @ emb_w + b); h0 -> SCR (stride 152)
    {
        v2f acc[9][2];
#pragma unroll
        for (int i = 0; i < 9; ++i)
#pragma unroll
            for (int g = 0; g < 2; ++g) { acc[i][g].x = 0.f; acc[i][g].y = 0.f; }
        gemm_acc<76, 150, 75, 2, true>(SCR, P.emb_w, acc, rbase, lane);
        __syncthreads();                      // all x reads done
#pragma unroll
        for (int i = 0; i < 9; ++i) {
            if (i < rcnt) {
#pragma unroll
                for (int g = 0; g < 2; ++g) {
                    int c = g * 128 + 2 * lane;
                    if (c < 150) {
                        v2f bv = *reinterpret_cast<const v2f*>(P.emb_b + c);
                        v2f v = acc[i][g] + bv;
                        v.x = fmaxf(v.x, 0.f); v.y = fmaxf(v.y, 0.f);
                        *reinterpret_cast<v2f*>(SCR + (size_t)(rbase + i) * 152 + c) = v;
                    }
                }
            }
        }
        __syncthreads();
    }
    // S1: t1 = h0 @ gc1_w -> bA (stride 256)
    {
        v2f acc[9][2];
#pragma unroll
        for (int i = 0; i < 9; ++i)
#pragma unroll
            for (int g = 0; g < 2; ++g) { acc[i][g].x = 0.f; acc[i][g].y = 0.f; }
        gemm_acc<152, 256, 150, 2, true>(SCR, P.gc1_w, acc, rbase, lane);
#pragma unroll
        for (int i = 0; i < 9; ++i) {
            if (i < rcnt) {
#pragma unroll
                for (int g = 0; g < 2; ++g) {
                    int c = g * 128 + 2 * lane;
                    *reinterpret_cast<v2f*>(bAg + (size_t)(rbase + i) * 256 + c) = acc[i][g];
                }
            }
        }
    }
    __syncthreads();
    // S2: y1 = relu(spmm(t1)+b1) -> bB (stride 256)
    for (int r = wave; r < NN; r += NW)
        spmm_row4(bAg, P.gc1_b, pairsS[r], cS[r], bBg + (size_t)r * 256, lane);
    __syncthreads();
    // S3: p1 = pool(y1) -> bC (stride 256)
    for (int r = wave; r < NN; r += NW)
        pool_row4(bBg, pairsS[r], cS[r].x, bCg + (size_t)r * 256, lane);
    __syncthreads();
    // S4: t2 = p1 @ gc2_w (two 128-col k-passes via SCR) -> SCR (stride 132)
    {
        v2f acc[9][1];
#pragma unroll
        for (int i = 0; i < 9; ++i) { acc[i][0].x = 0.f; acc[i][0].y = 0.f; }
        for (int kp = 0; kp < 2; ++kp) {
            for (int i = tid; i < NN * 32; i += 1024) {
                int r = i >> 5, c4 = (i & 31) * 4;
                *reinterpret_cast<v4f*>(SCR + r * 132 + c4) =
                    *reinterpret_cast<const v4f*>(bCg + (size_t)r * 256 + kp * 128 + c4);
            }
            __syncthreads();
            gemm_acc<132, 128, 128, 1, true>(SCR, P.gc2_w + kp * 128 * 128,
                                             acc, rbase, lane);
            __syncthreads();                  // SCR reads done before overwrite
        }
#pragma unroll
        for (int i = 0; i < 9; ++i) {
            if (i < rcnt)
                *reinterpret_cast<v2f*>(SCR + (size_t)(rbase + i) * 132 + 2 * lane) = acc[i][0];
        }
        __syncthreads();
    }
    // S5: y2 = relu(spmm(t2 LDS)+b2) -> bB (stride 128)
    for (int r = wave; r < NN; r += NW)
        spmm_row2(SCR, 132, 126, P.gc2_b, 128, pairsS[r], cS[r],
                  bBg + (size_t)r * 128, lane);
    __syncthreads();
    // S6: stage y2 -> SCR(132); p2 = pool(y2 LDS) -> bC (stride 128)
    for (int i = tid; i < NN * 32; i += 1024) {
        int r = i >> 5, c4 = (i & 31) * 4;
        *reinterpret_cast<v4f*>(SCR + r * 132 + c4) =
            *reinterpret_cast<const v4f*>(bBg + (size_t)r * 128 + c4);
    }
    __syncthreads();
    for (int r = wave; r < NN; r += NW)
        pool_row2(SCR, 132, 126, 128, pairsS[r], cS[r].x,
                  bCg + (size_t)r * 128, lane);
    __syncthreads();
    // S7: stage p2 -> SCR(132); t3 = p2 @ gc3_w -> SCR (stride 80, N=75)
    for (int i = tid; i < NN * 32; i += 1024) {
        int r = i >> 5, c4 = (i & 31) * 4;
        *reinterpret_cast<v4f*>(SCR + r * 132 + c4) =
            *reinterpret_cast<const v4f*>(bCg + (size_t)r * 128 + c4);
    }
    __syncthreads();
    {
        v2f acc[9][1];
#pragma unroll
        for (int i = 0; i < 9; ++i) { acc[i][0].x = 0.f; acc[i][0].y = 0.f; }
        gemm_acc<132, 75, 128, 1, false>(SCR, P.gc3_w, acc, rbase, lane);
        __syncthreads();                      // p2 reads done
        const int c0 = 2 * lane;
#pragma unroll
        for (int i = 0; i < 9; ++i) {
            if (i < rcnt && c0 < 75) {
                v2f o; o.x = acc[i][0].x;
                o.y = (c0 + 1 < 75) ? acc[i][0].y : 0.f;
                *reinterpret_cast<v2f*>(SCR + (size_t)(rbase + i) * 80 + c0) = o;
            }
        }
        __syncthreads();
    }
    // S8: y3 = relu(spmm(t3 LDS)+b3) -> bB (stride 76, N=75)
    for (int r = wave; r < NN; r += NW)
        spmm_row2(SCR, 80, 74, P.gc3_b, 75, pairsS[r], cS[r],
                  bBg + (size_t)r * 76, lane);
    __syncthreads();
    // S9: t4S[r] = pool3(y3)[r] . gc4_w
    for (int r = wave; r < NN; r += NW)
        t4_row_l(bBg, pairsS[r], cS[r].x, P.gc4_w, t4S, r, lane);
    __syncthreads();
    // S10: tail — y4 = relu(A@t4+b4); fc1; fin; sigmoid
    if (tid < NN) {
        const float2* pb = pairsS[tid];
        int2 c = cS[tid];
        float s = P.gc4_b[0];
        for (int q = 0; q < c.x; ++q) {
            float2 f = pb[q];
            s = fmaf(f.x, t4S[__float_as_int(f.y)], s);
        }
        for (int q = 0; q < c.y; ++q) {
            float2 f = pb[(NPAIR - 1) - q];
            s = fmaf(f.x, t4S[__float_as_int(f.y)], s);
        }
        y4S[tid] = fmaxf(s, 0.f);
    }
    __syncthreads();
    if (tid < 3) {
        float s = P.fc1_b[tid];
        for (int j = 0; j < 132; ++j)
            s = fmaf(y4S[1 + j], P.fc1_w[j * 3 + tid], s);
        rS[tid] = s;
    }
    __syncthreads();
    if (tid == 0) {
        float z = P.fin_b[0] + y4S[0] * P.fin_w[0] + rS[0] * P.fin_w[1]
                + rS[1] * P.fin_w[2] + rS[2] * P.fin_w[3];
        P.out[b] = 1.f / (1.f + expf(-z));
    }
}

extern "C" void kernel_launch(void* const* d_in, const int* in_sizes, int n_in,
                              void* d_out, int out_size, void* d_ws, size_t ws_size,
                              hipStream_t stream)
{
    const size_t MR = (size_t)64 * NN;           // 8512 rows
    float* bA = (float*)d_ws;
    float* bB = bA + MR * 256;
    float* bC = bB + MR * 256;

    Params hp;
    hp.x     = (const float*)d_in[0];
    hp.adj   = (const float*)d_in[1];
    hp.emb_w = (const float*)d_in[2];
    hp.emb_b = (const float*)d_in[3];
    hp.gc1_w = (const float*)d_in[4];
    hp.gc1_b = (const float*)d_in[5];
    hp.gc2_w = (const float*)d_in[6];
    hp.gc2_b = (const float*)d_in[7];
    hp.gc3_w = (const float*)d_in[8];
    hp.gc3_b = (const float*)d_in[9];
    hp.gc4_w = (const float*)d_in[10];
    hp.gc4_b = (const float*)d_in[11];
    hp.fc1_w = (const float*)d_in[12];
    hp.fc1_b = (const float*)d_in[13];
    hp.fin_w = (const float*)d_in[14];
    hp.fin_b = (const float*)d_in[15];
    hp.bA = bA; hp.bB = bB; hp.bC = bC;
    hp.out = (float*)d_out;

    hipLaunchKernelGGL(graph_k, dim3(64), dim3(1024), 0, stream, hp);
}

// Round 7
// 227.117 us; speedup vs baseline: 1.3103x; 1.3103x over previous
//
#include <hip/hip_runtime.h>
#include <math.h>

// ---------------------------------------------------------------------------
// B=64 graphs, NN=133 nodes. R-mfma: one block per graph (64 x 1024thr).
// Round-5 lesson: fp32 GEMM is latency/issue-bound and has a ~40us/graph
// VALU floor (24.5MF @ 256 FLOP/cy/CU); two different fp32 inner loops both
// landed ~220-237us. This round moves the 4 dense GEMMs to f16 MFMA
// (v_mfma_f32_16x16x32_f16, 16384 FLOP/instr -> ~109 MFMA/wave total):
//  - A staged as f16 in LDS (144-row zero-padded regions; strides 104/168/
//    264/136 are mult-of-8 for b128 frag reads and give <=2-way bank alias).
//  - B frags read per-lane from L2-hot global W + cvt (each W elem read
//    once per block).  C/D layout: col=lane&15, row=(lane>>4)*4+reg [m89].
//  - fp32 accumulate; f16 input rounding -> absmax ~1e-3 (< 7.58e-3 thr).
// Sparse stages (spmm/pool/t4/tail) byte-identical to validated round-5
// code, reading global activations (round-3/4 validated shapes):
//  zero+prep | x->f16 | emb(MFMA)->h0(LDS f16) | gemm1->bA | spmm1 | pool1 |
//  stage p1 | gemm2->bA(128) | spmm2 | pool2 | stage p2 | gemm3->bA(76,
//  col75=0) | spmm3 | t4 | tail
// LDS: SCRH f16 76.5KB + pairs 68.1KB + misc ~2KB = 146.6KB.
// ---------------------------------------------------------------------------

#define NN 133
#define NPAIR 64
#define NW 16
#define H0OFF 14976            // x region = 144*104 halfs; h0 = 144*168

typedef float v2f __attribute__((ext_vector_type(2)));
typedef float v4f __attribute__((ext_vector_type(4)));
typedef _Float16 f16x8 __attribute__((ext_vector_type(8)));
typedef float f32x4 __attribute__((ext_vector_type(4)));

struct Params {
    const float *x, *adj, *emb_w, *emb_b, *gc1_w, *gc1_b, *gc2_w, *gc2_b,
                *gc3_w, *gc3_b, *gc4_w, *gc4_b, *fc1_w, *fc1_b, *fin_w, *fin_b;
    float *bA, *bB, *bC;
    float *out;
};

// -------- ballot prep into LDS: front=a>1e-5, back=0<a<=1e-5 ----------------
__device__ __forceinline__ void prep_row_l(
    const float* __restrict__ ar, float2* __restrict__ pb,
    int2* __restrict__ cS, int r, int lane)
{
    const unsigned long long lt = (1ull << lane) - 1ull;
    int base0 = 0, base1 = 0;
#pragma unroll
    for (int s = 0; s < 3; ++s) {
        const int j = lane + 64 * s;
        const float a = (j < NN) ? ar[j] : 0.f;
        const bool f = a > 1e-5f;
        const bool g = (a > 0.f) && !f;
        const unsigned long long mf = __ballot(f);
        const unsigned long long mg = __ballot(g);
        if (f) pb[base0 + __popcll(mf & lt)] =
                   make_float2(a, __int_as_float(j));
        if (g) pb[(NPAIR - 1) - (base1 + __popcll(mg & lt))] =
                   make_float2(a, __int_as_float(j));
        base0 += __popcll(mf);
        base1 += __popcll(mg);
    }
    if (lane == 0) cS[r] = make_int2(base0, base1);
}

// -------- MFMA GEMM: out[r,c] = sum_k A[r,k] W[k,c] (+bias,relu opt) --------
// A: LDS f16, 144 rows (pad rows/k zeroed), stride LDA2 (mult of 8).
// W: global f32 [K][N].  Tiles: 9 row-tiles x NTC col-tiles, wave-strided.
// Store: col<STN; value = (col<N ? result : 0) -> STN=76/N=75 zeroes col 75.
template<int K, int KPAD, int LDA2, int N, int STN, int NTC,
         int LDO, int LDOL, bool RB, bool TO_LDS>
__device__ __forceinline__ void mfma_gemm(
    const _Float16* __restrict__ Af, const float* __restrict__ W,
    const float* __restrict__ bias, float* __restrict__ outg,
    _Float16* __restrict__ outl, int wave, int lane)
{
    const int lrow = lane & 15, lkb = lane >> 4;
    for (int t = wave; t < NTC * 9; t += NW) {
        const int ct = t % NTC, rt = t / NTC;
        const int col = ct * 16 + lrow;
        const int colc = min(col, N - 1);
        f32x4 acc = {0.f, 0.f, 0.f, 0.f};
#pragma unroll
        for (int ks = 0; ks < KPAD / 32; ++ks) {
            f16x8 a = *reinterpret_cast<const f16x8*>(
                Af + (rt * 16 + lrow) * LDA2 + ks * 32 + lkb * 8);
            f16x8 bf;
#pragma unroll
            for (int j = 0; j < 8; ++j) {
                const int kk = ks * 32 + lkb * 8 + j;
                float wv = W[(size_t)min(kk, K - 1) * N + colc];
                if (kk >= K || col >= N) wv = 0.f;
                bf[j] = (_Float16)wv;
            }
            acc = __builtin_amdgcn_mfma_f32_16x16x32_f16(a, bf, acc, 0, 0, 0);
        }
#pragma unroll
        for (int i = 0; i < 4; ++i) {
            const int row = rt * 16 + lkb * 4 + i;
            if (row < NN && col < STN) {
                float v = 0.f;
                if (col < N) {
                    v = acc[i];
                    if (RB) v = fmaxf(v + bias[col], 0.f);
                }
                if (TO_LDS) outl[row * LDOL + col] = (_Float16)v;
                else        outg[(size_t)row * LDO + col] = v;
            }
        }
    }
}

// -------- spmm (float4 cols, global source, N=256) --------------------------
__device__ __forceinline__ void spmm_row4(
    const float* __restrict__ tb,            // global, stride 256
    const float* __restrict__ bias,
    const float2* __restrict__ pb, int2 cc,
    float* __restrict__ yrow, int lane)
{
    const int c4 = 4 * lane;
    const float4* pq = reinterpret_cast<const float4*>(pb);
    v4f acc[4];
#pragma unroll
    for (int h = 0; h < 4; ++h) { acc[h].x = 0.f; acc[h].y = 0.f; acc[h].z = 0.f; acc[h].w = 0.f; }
    int q = 0;
    for (; q + 4 <= cc.x; q += 4) {
        float4 p0 = pq[q >> 1], p1 = pq[(q >> 1) + 1];
        float w[4]; int j[4];
        w[0] = p0.x; j[0] = __float_as_int(p0.y);
        w[1] = p0.z; j[1] = __float_as_int(p0.w);
        w[2] = p1.x; j[2] = __float_as_int(p1.y);
        w[3] = p1.z; j[3] = __float_as_int(p1.w);
#pragma unroll
        for (int h = 0; h < 4; ++h) {
            v4f r4 = *reinterpret_cast<const v4f*>(tb + (size_t)j[h] * 256 + c4);
            v4f wv; wv.x = w[h]; wv.y = w[h]; wv.z = w[h]; wv.w = w[h];
            acc[h] = __builtin_elementwise_fma(wv, r4, acc[h]);
        }
    }
    for (; q < cc.x; ++q) {
        float2 f = pb[q];
        v4f r4 = *reinterpret_cast<const v4f*>(tb + (size_t)__float_as_int(f.y) * 256 + c4);
        v4f wv; wv.x = f.x; wv.y = f.x; wv.z = f.x; wv.w = f.x;
        acc[0] = __builtin_elementwise_fma(wv, r4, acc[0]);
    }
    for (int v = 0; v < cc.y; ++v) {
        float2 f = pb[(NPAIR - 1) - v];
        v4f r4 = *reinterpret_cast<const v4f*>(tb + (size_t)__float_as_int(f.y) * 256 + c4);
        v4f wv; wv.x = f.x; wv.y = f.x; wv.z = f.x; wv.w = f.x;
        acc[0] = __builtin_elementwise_fma(wv, r4, acc[0]);
    }
    v4f s = (acc[0] + acc[1]) + (acc[2] + acc[3]);
    v4f bv = *reinterpret_cast<const v4f*>(bias + c4);
    s = s + bv;
    s.x = fmaxf(s.x, 0.f); s.y = fmaxf(s.y, 0.f);
    s.z = fmaxf(s.z, 0.f); s.w = fmaxf(s.w, 0.f);
    *reinterpret_cast<v4f*>(yrow + c4) = s;
}

// -------- pool (float4 cols, global source, N=256) --------------------------
__device__ __forceinline__ void pool_row4(
    const float* __restrict__ yb,
    const float2* __restrict__ pb, int cx,
    float* __restrict__ prow, int lane)
{
    const int c4 = 4 * lane;
    const float4* pq = reinterpret_cast<const float4*>(pb);
    v4f m[4];
#pragma unroll
    for (int h = 0; h < 4; ++h) { m[h].x = 0.f; m[h].y = 0.f; m[h].z = 0.f; m[h].w = 0.f; }
    int q = 0;
    for (; q + 4 <= cx; q += 4) {
        float4 p0 = pq[q >> 1], p1 = pq[(q >> 1) + 1];
        int j[4];
        j[0] = __float_as_int(p0.y); j[1] = __float_as_int(p0.w);
        j[2] = __float_as_int(p1.y); j[3] = __float_as_int(p1.w);
#pragma unroll
        for (int h = 0; h < 4; ++h) {
            v4f r4 = *reinterpret_cast<const v4f*>(yb + (size_t)j[h] * 256 + c4);
            m[h].x = fmaxf(m[h].x, r4.x); m[h].y = fmaxf(m[h].y, r4.y);
            m[h].z = fmaxf(m[h].z, r4.z); m[h].w = fmaxf(m[h].w, r4.w);
        }
    }
    for (; q < cx; ++q) {
        v4f r4 = *reinterpret_cast<const v4f*>(yb + (size_t)__float_as_int(pb[q].y) * 256 + c4);
        m[0].x = fmaxf(m[0].x, r4.x); m[0].y = fmaxf(m[0].y, r4.y);
        m[0].z = fmaxf(m[0].z, r4.z); m[0].w = fmaxf(m[0].w, r4.w);
    }
    v4f s;
    s.x = fmaxf(fmaxf(m[0].x, m[1].x), fmaxf(m[2].x, m[3].x));
    s.y = fmaxf(fmaxf(m[0].y, m[1].y), fmaxf(m[2].y, m[3].y));
    s.z = fmaxf(fmaxf(m[0].z, m[1].z), fmaxf(m[2].z, m[3].z));
    s.w = fmaxf(fmaxf(m[0].w, m[1].w), fmaxf(m[2].w, m[3].w));
    *reinterpret_cast<v4f*>(prow + c4) = s;
}

// -------- spmm (float2 cols, generic pointer source) ------------------------
__device__ __forceinline__ void spmm_row2(
    const float* __restrict__ tb, int ldt, int scmax,
    const float* __restrict__ bias, int N,
    const float2* __restrict__ pb, int2 cc,
    float* __restrict__ yrow, int lane)
{
    const int c0 = 2 * lane;
    const int sc = min(c0, scmax);
    const float4* pq = reinterpret_cast<const float4*>(pb);
    v2f acc[4];
#pragma unroll
    for (int h = 0; h < 4; ++h) { acc[h].x = 0.f; acc[h].y = 0.f; }
    int q = 0;
    for (; q + 4 <= cc.x; q += 4) {
        float4 p0 = pq[q >> 1], p1 = pq[(q >> 1) + 1];
        float w[4]; int j[4];
        w[0] = p0.x; j[0] = __float_as_int(p0.y);
        w[1] = p0.z; j[1] = __float_as_int(p0.w);
        w[2] = p1.x; j[2] = __float_as_int(p1.y);
        w[3] = p1.z; j[3] = __float_as_int(p1.w);
#pragma unroll
        for (int h = 0; h < 4; ++h) {
            v2f r2 = *reinterpret_cast<const v2f*>(tb + (size_t)j[h] * ldt + sc);
            v2f wv; wv.x = w[h]; wv.y = w[h];
            acc[h] = __builtin_elementwise_fma(wv, r2, acc[h]);
        }
    }
    for (; q < cc.x; ++q) {
        float2 f = pb[q];
        v2f r2 = *reinterpret_cast<const v2f*>(tb + (size_t)__float_as_int(f.y) * ldt + sc);
        v2f wv; wv.x = f.x; wv.y = f.x;
        acc[0] = __builtin_elementwise_fma(wv, r2, acc[0]);
    }
    for (int v = 0; v < cc.y; ++v) {
        float2 f = pb[(NPAIR - 1) - v];
        v2f r2 = *reinterpret_cast<const v2f*>(tb + (size_t)__float_as_int(f.y) * ldt + sc);
        v2f wv; wv.x = f.x; wv.y = f.x;
        acc[0] = __builtin_elementwise_fma(wv, r2, acc[0]);
    }
    v2f s = (acc[0] + acc[1]) + (acc[2] + acc[3]);
    float b0 = bias[min(c0, N - 1)];
    float b1 = (c0 + 1 < N) ? bias[c0 + 1] : 0.f;
    s.x = fmaxf(s.x + b0, 0.f);
    s.y = fmaxf(s.y + b1, 0.f);
    if (c0 < N) {
        v2f o; o.x = s.x; o.y = (c0 + 1 < N) ? s.y : 0.f;
        *reinterpret_cast<v2f*>(yrow + c0) = o;
    }
}

// -------- pool (float2 cols, generic pointer source) ------------------------
__device__ __forceinline__ void pool_row2(
    const float* __restrict__ yb, int ldt, int scmax, int N,
    const float2* __restrict__ pb, int cx,
    float* __restrict__ prow, int lane)
{
    const int c0 = 2 * lane;
    const int sc = min(c0, scmax);
    const float4* pq = reinterpret_cast<const float4*>(pb);
    v2f m[4];
#pragma unroll
    for (int h = 0; h < 4; ++h) { m[h].x = 0.f; m[h].y = 0.f; }
    int q = 0;
    for (; q + 4 <= cx; q += 4) {
        float4 p0 = pq[q >> 1], p1 = pq[(q >> 1) + 1];
        int j[4];
        j[0] = __float_as_int(p0.y); j[1] = __float_as_int(p0.w);
        j[2] = __float_as_int(p1.y); j[3] = __float_as_int(p1.w);
#pragma unroll
        for (int h = 0; h < 4; ++h) {
            v2f r2 = *reinterpret_cast<const v2f*>(yb + (size_t)j[h] * ldt + sc);
            m[h].x = fmaxf(m[h].x, r2.x); m[h].y = fmaxf(m[h].y, r2.y);
        }
    }
    for (; q < cx; ++q) {
        v2f r2 = *reinterpret_cast<const v2f*>(yb + (size_t)__float_as_int(pb[q].y) * ldt + sc);
        m[0].x = fmaxf(m[0].x, r2.x); m[0].y = fmaxf(m[0].y, r2.y);
    }
    v2f s;
    s.x = fmaxf(fmaxf(m[0].x, m[1].x), fmaxf(m[2].x, m[3].x));
    s.y = fmaxf(fmaxf(m[0].y, m[1].y), fmaxf(m[2].y, m[3].y));
    if (c0 < N) {
        v2f o; o.x = s.x; o.y = (c0 + 1 < N) ? s.y : 0.f;
        *reinterpret_cast<v2f*>(prow + c0) = o;
    }
}

// -------- t4: t4S[r] = dot(pool3(y3)[r,0:75], gc4_w) ------------------------
__device__ __forceinline__ void t4_row_l(
    const float* __restrict__ yb,            // y3 global, stride 76
    const float2* __restrict__ pb, int cx,
    const float* __restrict__ gc4_w,
    float* __restrict__ t4S, int r, int lane)
{
    const float4* pq = reinterpret_cast<const float4*>(pb);
    const float gw0 = gc4_w[lane];
    const float gw1 = (lane < 11) ? gc4_w[64 + lane] : 0.f;
    const int c2 = 64 + min(lane, 10);

    float m0a = 0.f, m1a = 0.f, m0b = 0.f, m1b = 0.f;
    float m0c = 0.f, m1c = 0.f, m0d = 0.f, m1d = 0.f;
    int q = 0;
    for (; q + 4 <= cx; q += 4) {
        float4 pA = pq[q >> 1], pB = pq[(q >> 1) + 1];
        const float* r0 = yb + (size_t)__float_as_int(pA.y) * 76;
        const float* r1 = yb + (size_t)__float_as_int(pA.w) * 76;
        const float* r2 = yb + (size_t)__float_as_int(pB.y) * 76;
        const float* r3 = yb + (size_t)__float_as_int(pB.w) * 76;
        m0a = fmaxf(m0a, r0[lane]); m1a = fmaxf(m1a, r0[c2]);
        m0b = fmaxf(m0b, r1[lane]); m1b = fmaxf(m1b, r1[c2]);
        m0c = fmaxf(m0c, r2[lane]); m1c = fmaxf(m1c, r2[c2]);
        m0d = fmaxf(m0d, r3[lane]); m1d = fmaxf(m1d, r3[c2]);
    }
    for (; q < cx; ++q) {
        const float* r0 = yb + (size_t)__float_as_int(pb[q].y) * 76;
        m0a = fmaxf(m0a, r0[lane]); m1a = fmaxf(m1a, r0[c2]);
    }
    float m0 = fmaxf(fmaxf(m0a, m0b), fmaxf(m0c, m0d));
    float m1 = fmaxf(fmaxf(m1a, m1b), fmaxf(m1c, m1d));
    float v = m0 * gw0 + m1 * gw1;
#pragma unroll
    for (int off = 32; off; off >>= 1) v += __shfl_xor(v, off, 64);
    if (lane == 0) t4S[r] = v;
}

// --------------------------- one block = one graph --------------------------
__global__ __launch_bounds__(1024, 1)
void graph_k(Params P)
{
    __shared__ __align__(16) _Float16 SCRH[39168];       // 76.5 KB f16 scratch
    __shared__ __align__(16) float2 pairsS[NN][NPAIR];   // 68.1 KB
    __shared__ int2  cS[NN];
    __shared__ float t4S[NN];
    __shared__ float y4S[NN];
    __shared__ float rS[3];

    const int b    = blockIdx.x;
    const int tid  = threadIdx.x;
    const int wave = tid >> 6, lane = tid & 63;

    float* bAg = P.bA + (size_t)b * NN * 256;
    float* bBg = P.bB + (size_t)b * NN * 256;
    float* bCg = P.bC + (size_t)b * NN * 256;

    // S0: zero f16 scratch (pads must be 0) + ballot prep
    for (int i = tid; i < 4896; i += 1024)
        reinterpret_cast<v4f*>(SCRH)[i] = v4f{0.f, 0.f, 0.f, 0.f};
    for (int r = wave; r < NN; r += NW)
        prep_row_l(P.adj + ((size_t)b * NN + r) * NN, pairsS[r], cS, r, lane);
    __syncthreads();
    // S0a: x -> f16 region 0 (144 x stride 104, K=75)
    for (int i = tid; i < NN * 75; i += 1024) {
        int r = i / 75, c = i - r * 75;
        SCRH[r * 104 + c] = (_Float16)P.x[(size_t)b * NN * 75 + i];
    }
    __syncthreads();
    // S0b: emb MFMA: h0 = relu(x@emb_w+b) -> f16 region H0OFF (stride 168)
    mfma_gemm<75, 96, 104, 150, 150, 10, 0, 168, true, true>(
        SCRH, P.emb_w, P.emb_b, nullptr, SCRH + H0OFF, wave, lane);
    __syncthreads();
    // S1: gemm1 MFMA: t1 = h0 @ gc1_w -> bA (f32, stride 256)
    mfma_gemm<150, 160, 168, 256, 256, 16, 256, 0, false, false>(
        SCRH + H0OFF, P.gc1_w, nullptr, bAg, nullptr, wave, lane);
    __syncthreads();
    // S2: y1 = relu(spmm(t1)+b1) -> bB (stride 256)
    for (int r = wave; r < NN; r += NW)
        spmm_row4(bAg, P.gc1_b, pairsS[r], cS[r], bBg + (size_t)r * 256, lane);
    __syncthreads();
    // S3: p1 = pool(y1) -> bC (stride 256)
    for (int r = wave; r < NN; r += NW)
        pool_row4(bBg, pairsS[r], cS[r].x, bCg + (size_t)r * 256, lane);
    __syncthreads();
    // S4: stage p1 -> f16 region 0 (144 x stride 264, K=256; pad rows 0)
    for (int i = tid; i < 144 * 128; i += 1024) {
        int r = i >> 7, c2 = (i & 127) * 2;
        v2f v = {0.f, 0.f};
        if (r < NN) v = *reinterpret_cast<const v2f*>(bCg + (size_t)r * 256 + c2);
        SCRH[r * 264 + c2]     = (_Float16)v.x;
        SCRH[r * 264 + c2 + 1] = (_Float16)v.y;
    }
    __syncthreads();
    // gemm2 MFMA: t2 = p1 @ gc2_w -> bA (f32, stride 128)
    mfma_gemm<256, 256, 264, 128, 128, 8, 128, 0, false, false>(
        SCRH, P.gc2_w, nullptr, bAg, nullptr, wave, lane);
    __syncthreads();
    // S5: y2 = relu(spmm(t2)+b2) -> bB (stride 128)
    for (int r = wave; r < NN; r += NW)
        spmm_row2(bAg, 128, 126, P.gc2_b, 128, pairsS[r], cS[r],
                  bBg + (size_t)r * 128, lane);
    __syncthreads();
    // S6: p2 = pool(y2) -> bC (stride 128)
    for (int r = wave; r < NN; r += NW)
        pool_row2(bBg, 128, 126, 128, pairsS[r], cS[r].x,
                  bCg + (size_t)r * 128, lane);
    __syncthreads();
    // S7: stage p2 -> f16 region 0 (144 x stride 136, K=128; pad rows 0)
    for (int i = tid; i < 144 * 64; i += 1024) {
        int r = i >> 6, c2 = (i & 63) * 2;
        v2f v = {0.f, 0.f};
        if (r < NN) v = *reinterpret_cast<const v2f*>(bCg + (size_t)r * 128 + c2);
        SCRH[r * 136 + c2]     = (_Float16)v.x;
        SCRH[r * 136 + c2 + 1] = (_Float16)v.y;
    }
    __syncthreads();
    // gemm3 MFMA: t3 = p2 @ gc3_w -> bA (f32, stride 76; col75 stored as 0)
    mfma_gemm<128, 128, 136, 75, 76, 5, 76, 0, false, false>(
        SCRH, P.gc3_w, nullptr, bAg, nullptr, wave, lane);
    __syncthreads();
    // S8: y3 = relu(spmm(t3)+b3) -> bB (stride 76, N=75)
    for (int r = wave; r < NN; r += NW)
        spmm_row2(bAg, 76, 74, P.gc3_b, 75, pairsS[r], cS[r],
                  bBg + (size_t)r * 76, lane);
    __syncthreads();
    // S9: t4S[r] = pool3(y3)[r] . gc4_w
    for (int r = wave; r < NN; r += NW)
        t4_row_l(bBg, pairsS[r], cS[r].x, P.gc4_w, t4S, r, lane);
    __syncthreads();
    // S10: tail — y4 = relu(A@t4+b4); fc1; fin; sigmoid
    if (tid < NN) {
        const float2* pb = pairsS[tid];
        int2 c = cS[tid];
        float s = P.gc4_b[0];
        for (int q = 0; q < c.x; ++q) {
            float2 f = pb[q];
            s = fmaf(f.x, t4S[__float_as_int(f.y)], s);
        }
        for (int q = 0; q < c.y; ++q) {
            float2 f = pb[(NPAIR - 1) - q];
            s = fmaf(f.x, t4S[__float_as_int(f.y)], s);
        }
        y4S[tid] = fmaxf(s, 0.f);
    }
    __syncthreads();
    if (tid < 3) {
        float s = P.fc1_b[tid];
        for (int j = 0; j < 132; ++j)
            s = fmaf(y4S[1 + j], P.fc1_w[j * 3 + tid], s);
        rS[tid] = s;
    }
    __syncthreads();
    if (tid == 0) {
        float z = P.fin_b[0] + y4S[0] * P.fin_w[0] + rS[0] * P.fin_w[1]
                + rS[1] * P.fin_w[2] + rS[2] * P.fin_w[3];
        P.out[b] = 1.f / (1.f + expf(-z));
    }
}

extern "C" void kernel_launch(void* const* d_in, const int* in_sizes, int n_in,
                              void* d_out, int out_size, void* d_ws, size_t ws_size,
                              hipStream_t stream)
{
    const size_t MR = (size_t)64 * NN;           // 8512 rows
    float* bA = (float*)d_ws;
    float* bB = bA + MR * 256;
    float* bC = bB + MR * 256;

    Params hp;
    hp.x     = (const float*)d_in[0];
    hp.adj   = (const float*)d_in[1];
    hp.emb_w = (const float*)d_in[2];
    hp.emb_b = (const float*)d_in[3];
    hp.gc1_w = (const float*)d_in[4];
    hp.gc1_b = (const float*)d_in[5];
    hp.gc2_w = (const float*)d_in[6];
    hp.gc2_b = (const float*)d_in[7];
    hp.gc3_w = (const float*)d_in[8];
    hp.gc3_b = (const float*)d_in[9];
    hp.gc4_w = (const float*)d_in[10];
    hp.gc4_b = (const float*)d_in[11];
    hp.fc1_w = (const float*)d_in[12];
    hp.fc1_b = (const float*)d_in[13];
    hp.fin_w = (const float*)d_in[14];
    hp.fin_b = (const float*)d_in[15];
    hp.bA = bA; hp.bB = bB; hp.bC = bC;
    hp.out = (float*)d_out;

    hipLaunchKernelGGL(graph_k, dim3(64), dim3(1024), 0, stream, hp);
}

// Round 8
// 188.650 us; speedup vs baseline: 1.5775x; 1.2039x over previous
//
#include <hip/hip_runtime.h>
#include <math.h>

// ---------------------------------------------------------------------------
// B=64 graphs, NN=133 nodes. R-pack: one block per graph (64 x 1024thr).
// Round-6 evidence: MFMA cut dispatch 237->140us; remaining time is latency:
// B-frag built from 8 scalar f32 loads + 8 cvts per MFMA, and sparse gathers
// hitting L2. (Bank-conflict counter 496k ~= 3us total - red herring.)
// This round:
//  - wpack_k prelude (194 blocks): all 4 W matrices converted ONCE to f16 in
//    exact MFMA-B fragment layout (199KB, L2-resident, shared by all blocks).
//    B-frag = one coalesced global_load_dwordx4. MFMA loop: ds_read + load +
//    mfma, nothing else.
//  - ALL activations in LDS f16: two ping-pong 144x264 buffers (148.5KB).
//    GEMMs write LDS directly; spmm/pool/t4 gathers are ~120cy ds_reads.
//    Zero global activation traffic. Pair lists move to global ws (per-block
//    private -> L2-local) to free the LDS.
// Buffer schedule (alternating, pads pre-zeroed, stores guarded row<133):
//  B1=x ; B0=h0(emb) ; B1=t1 ; B0=y1 ; B1=p1 ; B0=t2 ; B1=y2 ; B0=p2 ;
//  B1=t3 ; B0=y3 ; t4 ; tail.
// Precision: ~9 f16 hops on activations (~1.5e-3 rel) -> absmax ~1e-3,
// under the 7.58e-3 threshold.
// ---------------------------------------------------------------------------

#define NN 133
#define NPAIR 64
#define NW 16
#define ST 264                 // LDS activation row stride (halfs); 132 dw = 4 mod 32

typedef float v4f __attribute__((ext_vector_type(4)));
typedef _Float16 f16x8 __attribute__((ext_vector_type(8)));
typedef _Float16 f16x4 __attribute__((ext_vector_type(4)));
typedef float f32x4 __attribute__((ext_vector_type(4)));

// packed-W segment offsets in halfs: tiles of 512 halfs = [64 lanes][8 halfs]
#define WP_EMB 0               // 10 ct * 3 ks
#define WP_GC1 15360           // 16 ct * 5 ks
#define WP_GC2 56320           // 8 ct * 8 ks
#define WP_GC3 89088           // 5 ct * 4 ks
#define WP_TOT 99328

struct Params {
    const float *x, *adj, *emb_w, *emb_b, *gc1_w, *gc1_b, *gc2_w, *gc2_b,
                *gc3_w, *gc3_b, *gc4_w, *gc4_b, *fc1_w, *fc1_b, *fin_w, *fin_b;
    const _Float16 *wp;
    float2 *gpairs;
    float *out;
};

// -------- W -> f16 fragment pack (194 blocks x 64 threads) ------------------
__global__ __launch_bounds__(64)
void wpack_k(const float* __restrict__ emb_w, const float* __restrict__ gc1_w,
             const float* __restrict__ gc2_w, const float* __restrict__ gc3_w,
             _Float16* __restrict__ wp)
{
    const int t = blockIdx.x, lane = threadIdx.x;
    const float* W; int K, N, NKS, off, u;
    if (t < 30)       { W = emb_w; K = 75;  N = 150; NKS = 3; off = WP_EMB; u = t; }
    else if (t < 110) { W = gc1_w; K = 150; N = 256; NKS = 5; off = WP_GC1; u = t - 30; }
    else if (t < 174) { W = gc2_w; K = 256; N = 128; NKS = 8; off = WP_GC2; u = t - 110; }
    else              { W = gc3_w; K = 128; N = 75;  NKS = 4; off = WP_GC3; u = t - 174; }
    const int ct = u / NKS, ks = u % NKS;
    const int col = ct * 16 + (lane & 15);
    const int kb  = ks * 32 + (lane >> 4) * 8;
    f16x8 v;
#pragma unroll
    for (int j = 0; j < 8; ++j) {
        const int kk = kb + j;
        float w = W[(size_t)min(kk, K - 1) * N + min(col, N - 1)];
        if (kk >= K || col >= N) w = 0.f;
        v[j] = (_Float16)w;
    }
    *reinterpret_cast<f16x8*>(wp + (size_t)off + (size_t)u * 512 + lane * 8) = v;
}

// -------- ballot prep: pairs -> GLOBAL, counts -> LDS -----------------------
__device__ __forceinline__ void prep_row_g(
    const float* __restrict__ ar, float2* __restrict__ pb,
    int2* __restrict__ cS, int r, int lane)
{
    const unsigned long long lt = (1ull << lane) - 1ull;
    int base0 = 0, base1 = 0;
#pragma unroll
    for (int s = 0; s < 3; ++s) {
        const int j = lane + 64 * s;
        const float a = (j < NN) ? ar[j] : 0.f;
        const bool f = a > 1e-5f;
        const bool g = (a > 0.f) && !f;
        const unsigned long long mf = __ballot(f);
        const unsigned long long mg = __ballot(g);
        if (f) pb[base0 + __popcll(mf & lt)] =
                   make_float2(a, __int_as_float(j));
        if (g) pb[(NPAIR - 1) - (base1 + __popcll(mg & lt))] =
                   make_float2(a, __int_as_float(j));
        base0 += __popcll(mf);
        base1 += __popcll(mg);
    }
    if (lane == 0) cS[r] = make_int2(base0, base1);
}

// -------- MFMA GEMM: A(LDS f16, stride ST) @ Wpack -> out (LDS f16) ---------
// C/D layout [m89]: col=lane&15, row=(lane>>4)*4+i.
template<int KPAD, int N, int STN, int NTC, bool RB>
__device__ __forceinline__ void mfma_gemm(
    const _Float16* __restrict__ Af, const _Float16* __restrict__ Wp,
    const float* __restrict__ bias, _Float16* __restrict__ outl,
    int wave, int lane)
{
    const int lrow = lane & 15, lkb = lane >> 4;
    for (int t = wave; t < NTC * 9; t += NW) {
        const int ct = t % NTC, rt = t / NTC;
        const int col = ct * 16 + lrow;
        const _Float16* ap  = Af + (rt * 16 + lrow) * ST + lkb * 8;
        const _Float16* wpt = Wp + (size_t)(ct * (KPAD / 32)) * 512 + lane * 8;
        f32x4 acc = {0.f, 0.f, 0.f, 0.f};
#pragma unroll
        for (int ks = 0; ks < KPAD / 32; ++ks) {
            f16x8 a  = *reinterpret_cast<const f16x8*>(ap + ks * 32);
            f16x8 bf = *reinterpret_cast<const f16x8*>(wpt + ks * 512);
            acc = __builtin_amdgcn_mfma_f32_16x16x32_f16(a, bf, acc, 0, 0, 0);
        }
#pragma unroll
        for (int i = 0; i < 4; ++i) {
            const int row = rt * 16 + lkb * 4 + i;
            if (row < NN && col < STN) {
                float v = 0.f;
                if (col < N) {
                    v = acc[i];
                    if (RB) v = fmaxf(v + bias[col], 0.f);
                }
                outl[row * ST + col] = (_Float16)v;
            }
        }
    }
}

// -------- spmm, 4 cols/lane (N=256), LDS f16 source/dest --------------------
__device__ __forceinline__ void spmm4_lds(
    const _Float16* __restrict__ tb, const float* __restrict__ bias,
    const float2* __restrict__ pb, int2 cc,
    _Float16* __restrict__ yrow, int lane)
{
    const int c0 = 4 * lane;
    const float4* pq = reinterpret_cast<const float4*>(pb);
    float a0[4] = {}, a1[4] = {}, a2[4] = {}, a3[4] = {};
    int q = 0;
    for (; q + 4 <= cc.x; q += 4) {
        float4 p0 = pq[q >> 1], p1 = pq[(q >> 1) + 1];
        f16x4 r0 = *(const f16x4*)(tb + __float_as_int(p0.y) * ST + c0);
        f16x4 r1 = *(const f16x4*)(tb + __float_as_int(p0.w) * ST + c0);
        f16x4 r2 = *(const f16x4*)(tb + __float_as_int(p1.y) * ST + c0);
        f16x4 r3 = *(const f16x4*)(tb + __float_as_int(p1.w) * ST + c0);
#pragma unroll
        for (int u = 0; u < 4; ++u) {
            a0[u] = fmaf(p0.x, (float)r0[u], a0[u]);
            a1[u] = fmaf(p0.z, (float)r1[u], a1[u]);
            a2[u] = fmaf(p1.x, (float)r2[u], a2[u]);
            a3[u] = fmaf(p1.z, (float)r3[u], a3[u]);
        }
    }
    for (; q < cc.x; ++q) {
        float2 f = pb[q];
        f16x4 r = *(const f16x4*)(tb + __float_as_int(f.y) * ST + c0);
#pragma unroll
        for (int u = 0; u < 4; ++u) a0[u] = fmaf(f.x, (float)r[u], a0[u]);
    }
    for (int v = 0; v < cc.y; ++v) {
        float2 f = pb[(NPAIR - 1) - v];
        f16x4 r = *(const f16x4*)(tb + __float_as_int(f.y) * ST + c0);
#pragma unroll
        for (int u = 0; u < 4; ++u) a0[u] = fmaf(f.x, (float)r[u], a0[u]);
    }
    f16x4 o;
#pragma unroll
    for (int u = 0; u < 4; ++u) {
        float s = (a0[u] + a1[u]) + (a2[u] + a3[u]);
        o[u] = (_Float16)fmaxf(s + bias[c0 + u], 0.f);
    }
    *(f16x4*)(yrow + c0) = o;
}

// -------- pool, 4 cols/lane (N=256) -----------------------------------------
__device__ __forceinline__ void pool4_lds(
    const _Float16* __restrict__ yb,
    const float2* __restrict__ pb, int cx,
    _Float16* __restrict__ prow, int lane)
{
    const int c0 = 4 * lane;
    const float4* pq = reinterpret_cast<const float4*>(pb);
    float m0[4] = {}, m1[4] = {}, m2[4] = {}, m3[4] = {};
    int q = 0;
    for (; q + 4 <= cx; q += 4) {
        float4 p0 = pq[q >> 1], p1 = pq[(q >> 1) + 1];
        f16x4 r0 = *(const f16x4*)(yb + __float_as_int(p0.y) * ST + c0);
        f16x4 r1 = *(const f16x4*)(yb + __float_as_int(p0.w) * ST + c0);
        f16x4 r2 = *(const f16x4*)(yb + __float_as_int(p1.y) * ST + c0);
        f16x4 r3 = *(const f16x4*)(yb + __float_as_int(p1.w) * ST + c0);
#pragma unroll
        for (int u = 0; u < 4; ++u) {
            m0[u] = fmaxf(m0[u], (float)r0[u]);
            m1[u] = fmaxf(m1[u], (float)r1[u]);
            m2[u] = fmaxf(m2[u], (float)r2[u]);
            m3[u] = fmaxf(m3[u], (float)r3[u]);
        }
    }
    for (; q < cx; ++q) {
        f16x4 r = *(const f16x4*)(yb + __float_as_int(pb[q].y) * ST + c0);
#pragma unroll
        for (int u = 0; u < 4; ++u) m0[u] = fmaxf(m0[u], (float)r[u]);
    }
    f16x4 o;
#pragma unroll
    for (int u = 0; u < 4; ++u)
        o[u] = (_Float16)fmaxf(fmaxf(m0[u], m1[u]), fmaxf(m2[u], m3[u]));
    *(f16x4*)(prow + c0) = o;
}

// -------- spmm, 2 cols/lane (N=128 or 75); c0 even => aligned ---------------
__device__ __forceinline__ void spmm2_lds(
    const _Float16* __restrict__ tb, const float* __restrict__ bias, int N,
    const float2* __restrict__ pb, int2 cc,
    _Float16* __restrict__ yrow, int lane)
{
    const int c0 = 2 * lane;                 // reads in-bounds of ST even if >=N
    const float4* pq = reinterpret_cast<const float4*>(pb);
    float a0[2] = {}, a1[2] = {}, a2[2] = {}, a3[2] = {};
    int q = 0;
    for (; q + 4 <= cc.x; q += 4) {
        float4 p0 = pq[q >> 1], p1 = pq[(q >> 1) + 1];
        f16x4 rr0 = *(const f16x4*)nullptr, rr1;
        (void)rr0; (void)rr1;
        const _Float16* t0 = tb + __float_as_int(p0.y) * ST + c0;
        const _Float16* t1 = tb + __float_as_int(p0.w) * ST + c0;
        const _Float16* t2 = tb + __float_as_int(p1.y) * ST + c0;
        const _Float16* t3 = tb + __float_as_int(p1.w) * ST + c0;
#pragma unroll
        for (int u = 0; u < 2; ++u) {
            a0[u] = fmaf(p0.x, (float)t0[u], a0[u]);
            a1[u] = fmaf(p0.z, (float)t1[u], a1[u]);
            a2[u] = fmaf(p1.x, (float)t2[u], a2[u]);
            a3[u] = fmaf(p1.z, (float)t3[u], a3[u]);
        }
    }
    for (; q < cc.x; ++q) {
        float2 f = pb[q];
        const _Float16* t0 = tb + __float_as_int(f.y) * ST + c0;
#pragma unroll
        for (int u = 0; u < 2; ++u) a0[u] = fmaf(f.x, (float)t0[u], a0[u]);
    }
    for (int v = 0; v < cc.y; ++v) {
        float2 f = pb[(NPAIR - 1) - v];
        const _Float16* t0 = tb + __float_as_int(f.y) * ST + c0;
#pragma unroll
        for (int u = 0; u < 2; ++u) a0[u] = fmaf(f.x, (float)t0[u], a0[u]);
    }
    float s0 = (a0[0] + a1[0]) + (a2[0] + a3[0]);
    float s1 = (a0[1] + a1[1]) + (a2[1] + a3[1]);
    s0 = fmaxf(s0 + bias[min(c0, N - 1)], 0.f);
    s1 = fmaxf(s1 + bias[min(c0 + 1, N - 1)], 0.f);
    if (c0 + 1 < N) {
        yrow[c0] = (_Float16)s0; yrow[c0 + 1] = (_Float16)s1;
    } else if (c0 < N) {
        yrow[c0] = (_Float16)s0;
    }
}

// -------- pool, 2 cols/lane (N=128) -----------------------------------------
__device__ __forceinline__ void pool2_lds(
    const _Float16* __restrict__ yb, int N,
    const float2* __restrict__ pb, int cx,
    _Float16* __restrict__ prow, int lane)
{
    const int c0 = 2 * lane;
    const float4* pq = reinterpret_cast<const float4*>(pb);
    float m0[2] = {}, m1[2] = {}, m2[2] = {}, m3[2] = {};
    int q = 0;
    for (; q + 4 <= cx; q += 4) {
        float4 p0 = pq[q >> 1], p1 = pq[(q >> 1) + 1];
        const _Float16* t0 = yb + __float_as_int(p0.y) * ST + c0;
        const _Float16* t1 = yb + __float_as_int(p0.w) * ST + c0;
        const _Float16* t2 = yb + __float_as_int(p1.y) * ST + c0;
        const _Float16* t3 = yb + __float_as_int(p1.w) * ST + c0;
#pragma unroll
        for (int u = 0; u < 2; ++u) {
            m0[u] = fmaxf(m0[u], (float)t0[u]);
            m1[u] = fmaxf(m1[u], (float)t1[u]);
            m2[u] = fmaxf(m2[u], (float)t2[u]);
            m3[u] = fmaxf(m3[u], (float)t3[u]);
        }
    }
    for (; q < cx; ++q) {
        const _Float16* t0 = yb + __float_as_int(pb[q].y) * ST + c0;
#pragma unroll
        for (int u = 0; u < 2; ++u) m0[u] = fmaxf(m0[u], (float)t0[u]);
    }
    if (c0 + 1 < N) {
        prow[c0]     = (_Float16)fmaxf(fmaxf(m0[0], m1[0]), fmaxf(m2[0], m3[0]));
        prow[c0 + 1] = (_Float16)fmaxf(fmaxf(m0[1], m1[1]), fmaxf(m2[1], m3[1]));
    } else if (c0 < N) {
        prow[c0]     = (_Float16)fmaxf(fmaxf(m0[0], m1[0]), fmaxf(m2[0], m3[0]));
    }
}

// -------- t4: t4S[r] = dot(pool3(y3 f16)[r,0:75], gc4_w) --------------------
__device__ __forceinline__ void t4_row_h(
    const _Float16* __restrict__ yb,         // y3 in LDS f16, stride ST
    const float2* __restrict__ pb, int cx,
    const float* __restrict__ gc4_w,
    float* __restrict__ t4S, int r, int lane)
{
    const float4* pq = reinterpret_cast<const float4*>(pb);
    const float gw0 = gc4_w[lane];
    const float gw1 = (lane < 11) ? gc4_w[64 + lane] : 0.f;
    const int c2 = 64 + min(lane, 10);

    float m0a = 0.f, m1a = 0.f, m0b = 0.f, m1b = 0.f;
    float m0c = 0.f, m1c = 0.f, m0d = 0.f, m1d = 0.f;
    int q = 0;
    for (; q + 4 <= cx; q += 4) {
        float4 pA = pq[q >> 1], pB = pq[(q >> 1) + 1];
        const _Float16* r0 = yb + __float_as_int(pA.y) * ST;
        const _Float16* r1 = yb + __float_as_int(pA.w) * ST;
        const _Float16* r2 = yb + __float_as_int(pB.y) * ST;
        const _Float16* r3 = yb + __float_as_int(pB.w) * ST;
        m0a = fmaxf(m0a, (float)r0[lane]); m1a = fmaxf(m1a, (float)r0[c2]);
        m0b = fmaxf(m0b, (float)r1[lane]); m1b = fmaxf(m1b, (float)r1[c2]);
        m0c = fmaxf(m0c, (float)r2[lane]); m1c = fmaxf(m1c, (float)r2[c2]);
        m0d = fmaxf(m0d, (float)r3[lane]); m1d = fmaxf(m1d, (float)r3[c2]);
    }
    for (; q < cx; ++q) {
        const _Float16* r0 = yb + __float_as_int(pb[q].y) * ST;
        m0a = fmaxf(m0a, (float)r0[lane]); m1a = fmaxf(m1a, (float)r0[c2]);
    }
    float m0 = fmaxf(fmaxf(m0a, m0b), fmaxf(m0c, m0d));
    float m1 = fmaxf(fmaxf(m1a, m1b), fmaxf(m1c, m1d));
    float v = m0 * gw0 + m1 * gw1;
#pragma unroll
    for (int off = 32; off; off >>= 1) v += __shfl_xor(v, off, 64);
    if (lane == 0) t4S[r] = v;
}

// --------------------------- one block = one graph --------------------------
__global__ __launch_bounds__(1024, 1)
void graph_k(Params P)
{
    __shared__ __align__(16) _Float16 BUF[2][144 * ST];  // 148.5 KB
    __shared__ int2  cS[NN];
    __shared__ float t4S[NN];
    __shared__ float y4S[NN];
    __shared__ float rS[3];

    const int b    = blockIdx.x;
    const int tid  = threadIdx.x;
    const int wave = tid >> 6, lane = tid & 63;

    _Float16* B0 = BUF[0];
    _Float16* B1 = BUF[1];
    float2* gp = P.gpairs + (size_t)b * NN * NPAIR;

    // S0: zero both buffers (pads must be 0)
    {
        v4f* z = reinterpret_cast<v4f*>(&BUF[0][0]);
        for (int i = tid; i < 2 * 144 * ST / 8; i += 1024)
            z[i] = v4f{0.f, 0.f, 0.f, 0.f};
    }
    __syncthreads();
    // S0a: x -> B1 f16 + ballot prep -> gpairs(global)/cS(LDS)
    for (int i = tid; i < NN * 75; i += 1024) {
        int r = i / 75, c = i - r * 75;
        B1[r * ST + c] = (_Float16)P.x[(size_t)b * NN * 75 + i];
    }
    for (int r = wave; r < NN; r += NW)
        prep_row_g(P.adj + ((size_t)b * NN + r) * NN, gp + (size_t)r * NPAIR,
                   cS, r, lane);
    __syncthreads();
    // S0b: emb: h0 = relu(x@emb_w+b) -> B0   (K=75,KPAD=96,N=150)
    mfma_gemm<96, 150, 150, 10, true>(B1, P.wp + WP_EMB, P.emb_b, B0, wave, lane);
    __syncthreads();
    // S1: t1 = h0 @ gc1_w -> B1   (K=150,KPAD=160,N=256)
    mfma_gemm<160, 256, 256, 16, false>(B0, P.wp + WP_GC1, nullptr, B1, wave, lane);
    __syncthreads();
    // S2: y1 = relu(spmm(t1)+b1) -> B0
    for (int r = wave; r < NN; r += NW)
        spmm4_lds(B1, P.gc1_b, gp + (size_t)r * NPAIR, cS[r],
                  B0 + r * ST, lane);
    __syncthreads();
    // S3: p1 = pool(y1) -> B1
    for (int r = wave; r < NN; r += NW)
        pool4_lds(B0, gp + (size_t)r * NPAIR, cS[r].x, B1 + r * ST, lane);
    __syncthreads();
    // S4: t2 = p1 @ gc2_w -> B0   (K=256,N=128)
    mfma_gemm<256, 128, 128, 8, false>(B1, P.wp + WP_GC2, nullptr, B0, wave, lane);
    __syncthreads();
    // S5: y2 = relu(spmm(t2)+b2) -> B1
    for (int r = wave; r < NN; r += NW)
        spmm2_lds(B0, P.gc2_b, 128, gp + (size_t)r * NPAIR, cS[r],
                  B1 + r * ST, lane);
    __syncthreads();
    // S6: p2 = pool(y2) -> B0
    for (int r = wave; r < NN; r += NW)
        pool2_lds(B1, 128, gp + (size_t)r * NPAIR, cS[r].x, B0 + r * ST, lane);
    __syncthreads();
    // S7: t3 = p2 @ gc3_w -> B1   (K=128,N=75; col75 stored 0)
    mfma_gemm<128, 75, 76, 5, false>(B0, P.wp + WP_GC3, nullptr, B1, wave, lane);
    __syncthreads();
    // S8: y3 = relu(spmm(t3)+b3) -> B0 (N=75)
    for (int r = wave; r < NN; r += NW)
        spmm2_lds(B1, P.gc3_b, 75, gp + (size_t)r * NPAIR, cS[r],
                  B0 + r * ST, lane);
    __syncthreads();
    // S9: t4S[r] = pool3(y3)[r] . gc4_w
    for (int r = wave; r < NN; r += NW)
        t4_row_h(B0, gp + (size_t)r * NPAIR, cS[r].x, P.gc4_w, t4S, r, lane);
    __syncthreads();
    // S10: tail — y4 = relu(A@t4+b4); fc1; fin; sigmoid
    if (tid < NN) {
        const float2* pb = gp + (size_t)tid * NPAIR;
        int2 c = cS[tid];
        float s = P.gc4_b[0];
        for (int q = 0; q < c.x; ++q) {
            float2 f = pb[q];
            s = fmaf(f.x, t4S[__float_as_int(f.y)], s);
        }
        for (int q = 0; q < c.y; ++q) {
            float2 f = pb[(NPAIR - 1) - q];
            s = fmaf(f.x, t4S[__float_as_int(f.y)], s);
        }
        y4S[tid] = fmaxf(s, 0.f);
    }
    __syncthreads();
    if (tid < 3) {
        float s = P.fc1_b[tid];
        for (int j = 0; j < 132; ++j)
            s = fmaf(y4S[1 + j], P.fc1_w[j * 3 + tid], s);
        rS[tid] = s;
    }
    __syncthreads();
    if (tid == 0) {
        float z = P.fin_b[0] + y4S[0] * P.fin_w[0] + rS[0] * P.fin_w[1]
                + rS[1] * P.fin_w[2] + rS[2] * P.fin_w[3];
        P.out[b] = 1.f / (1.f + expf(-z));
    }
}

extern "C" void kernel_launch(void* const* d_in, const int* in_sizes, int n_in,
                              void* d_out, int out_size, void* d_ws, size_t ws_size,
                              hipStream_t stream)
{
    // ws: wpack 199KB (padded to 256KB) | gpairs 4.36MB
    _Float16* wp = (_Float16*)d_ws;
    float2* gpairs = (float2*)((char*)d_ws + (256 << 10));

    Params hp;
    hp.x     = (const float*)d_in[0];
    hp.adj   = (const float*)d_in[1];
    hp.emb_w = (const float*)d_in[2];
    hp.emb_b = (const float*)d_in[3];
    hp.gc1_w = (const float*)d_in[4];
    hp.gc1_b = (const float*)d_in[5];
    hp.gc2_w = (const float*)d_in[6];
    hp.gc2_b = (const float*)d_in[7];
    hp.gc3_w = (const float*)d_in[8];
    hp.gc3_b = (const float*)d_in[9];
    hp.gc4_w = (const float*)d_in[10];
    hp.gc4_b = (const float*)d_in[11];
    hp.fc1_w = (const float*)d_in[12];
    hp.fc1_b = (const float*)d_in[13];
    hp.fin_w = (const float*)d_in[14];
    hp.fin_b = (const float*)d_in[15];
    hp.wp = wp;
    hp.gpairs = gpairs;
    hp.out = (float*)d_out;

    hipLaunchKernelGGL(wpack_k, dim3(194), dim3(64), 0, stream,
                       hp.emb_w, hp.gc1_w, hp.gc2_w, hp.gc3_w, wp);
    hipLaunchKernelGGL(graph_k, dim3(64), dim3(1024), 0, stream, hp);
}